// Round 15
// baseline (348.039 us; speedup 1.0000x reference)
//
#include <hip/hip_runtime.h>

#define S_LEN 1024
#define BATCH 8
#define EMB   1024
#define NH    16
#define HD    64
#define FFD   4096
#define ROWS  (S_LEN*BATCH)   // 8192

typedef __attribute__((ext_vector_type(8))) short  short8;
typedef __attribute__((ext_vector_type(4))) float  float4v;
typedef __attribute__((ext_vector_type(4))) unsigned int uint4v;

struct alignas(8) us4 { unsigned short x, y, z, w; };

__device__ __forceinline__ unsigned short f2bf(float f) {
    unsigned int u = __float_as_uint(f);
    u += 0x7fffu + ((u >> 16) & 1u);       // round-to-nearest-even
    return (unsigned short)(u >> 16);
}
__device__ __forceinline__ float bf2f(unsigned short b) {
    return __uint_as_float((unsigned int)b << 16);
}
__device__ __forceinline__ unsigned int cvtpk_bf16(float lo, float hi) {
    unsigned int r;
    asm("v_cvt_pk_bf16_f32 %0, %1, %2" : "=v"(r) : "v"(lo), "v"(hi));
    return r;
}
__device__ __forceinline__ float exp2v(float x) {   // v_exp_f32 = 2^x
    float r;
    asm("v_exp_f32 %0, %1" : "=v"(r) : "v"(x));
    return r;
}

__device__ __forceinline__ void gload_lds16(const void* g, void* l) {
    __builtin_amdgcn_global_load_lds(
        (const __attribute__((address_space(1))) unsigned int*)g,
        (__attribute__((address_space(3))) unsigned int*)l, 16, 0, 0);
}

// LDS byte offset for element-row `row` (128B pitch = 64 bf16) and 16B chunk
// `chunk`, XOR-swizzled so ds_read_b128 phases are conflict-free.
__device__ __forceinline__ int swz(int row, int chunk) {
    return (row << 7) + ((chunk ^ (row & 7)) << 4);
}

// XCD-aware decode (T1): 1-D grid, nwg%8==0, M-panels = 32. Blocks with the
// same m-panel (ly) share id%8 -> same XCD -> A-panel L2-filled once per XCD.
__device__ __forceinline__ void xcd_decode(int id, int& lx, int& ly) {
    int k = id & 7, j = id >> 3;
    ly = k * 4 + (j & 3);
    lx = j >> 2;
}

// ---------------------------------------------------------------- cast f32->bf16
__global__ __launch_bounds__(256) void cast_bf(const float* __restrict__ in,
                                               unsigned short* __restrict__ out,
                                               int n4) {
    int i = blockIdx.x * 256 + threadIdx.x;
    if (i >= n4) return;
    float4 v = ((const float4*)in)[i];
    us4 o = { f2bf(v.x), f2bf(v.y), f2bf(v.z), f2bf(v.w) };
    ((us4*)out)[i] = o;
}

// ================================================================ 256x128 1-barrier GEMM
// (r12-proven structure, now carries ALL four GEMMs.) C = A * B^T.
// 512 thr = 8 waves (4M x 2N), wave owns 64x64. Triple-buffered LDS
// (A 3x32K + B 3x16K = 144K), 2-deep prefetch, ONE s_barrier + one
// lgkmcnt(0) + one counted vmcnt(6) per K-tile (never drains to 0 -- T4).
// Race-safety (verified r12): tile t's loads drained by vmcnt(6) at end of
// iter t-1 BEFORE the barrier all waves cross ahead of reading slot t%3 (RAW);
// stage(t+2) overwrites slot (t-1)%3 whose iter-(t-1) reads retired at that
// iter's lgkmcnt(0) before its end barrier (WAR).
// MODE 0: bf16 out = (acc+bias)*(col<EMB?QSCALE:1)   (QKV)
// MODE 1: f32  out = acc+bias+res_f32                 (out-proj + src)
// MODE 2: bf16 out = relu(acc+bias)                   (FF1)
// MODE 3: f32  out = acc+bias+res_bf16                (FF2 + x)
#define QSCALE 0.18033688011112042f    // 0.125 * log2(e): softmax runs in exp2 units
template <int MODE>
__global__ __launch_bounds__(512, 2) void gemm256n(const unsigned short* __restrict__ A,
                                                   const unsigned short* __restrict__ Bw,
                                                   const float* __restrict__ bias,
                                                   const float* __restrict__ res,
                                                   const unsigned short* __restrict__ resb,
                                                   float* __restrict__ outf,
                                                   unsigned short* __restrict__ outb,
                                                   int M, int N, int K) {
    __shared__ char lds[147456];   // A: [0,96K) 3x32K slots; B: [96K,144K) 3x16K
    const int tid = threadIdx.x, lane = tid & 63, w = tid >> 6;
    const int wr = w >> 1, wc = w & 1;     // 4M x 2N
    int lx, ly;
    xcd_decode(blockIdx.x, lx, ly);
    const int m0 = ly * 256, n0 = lx * 128;
    const int nt = K >> 6;
    const int g = lane >> 4, qs = lane & 15;

    size_t baseA[4], baseB[2];
    int ldsOffA[4], ldsOffB[2];
#pragma unroll
    for (int q = 0; q < 4; ++q) {
        int ci = q * 512 + tid;
        int row = ci >> 3;                 // 0..255
        int c = (ci & 7) ^ (row & 7);
        baseA[q] = (size_t)(m0 + row) * K + c * 8;
        ldsOffA[q] = ci * 16;
    }
#pragma unroll
    for (int q = 0; q < 2; ++q) {
        int ci = q * 512 + tid;
        int row = ci >> 3;                 // 0..127
        int c = (ci & 7) ^ (row & 7);
        baseB[q] = (size_t)(n0 + row) * K + c * 8;
        ldsOffB[q] = ci * 16;
    }

    auto stage = [&](int kt) {
        int ktc = kt < nt ? kt : 0;        // clamp: garbage lands, never read
        int slot = kt % 3;
#pragma unroll
        for (int q = 0; q < 4; ++q)
            gload_lds16(A + baseA[q] + (size_t)ktc * 64,
                        lds + slot * 32768 + ldsOffA[q]);
#pragma unroll
        for (int q = 0; q < 2; ++q)
            gload_lds16(Bw + baseB[q] + (size_t)ktc * 64,
                        lds + 98304 + slot * 16384 + ldsOffB[q]);
    };

    auto rdA = [&](int slot, int i, int mk) -> short8 {
        int arow = wr * 64 + i * 16 + qs;
        return *(const short8*)(lds + slot * 32768 + swz(arow, mk * 4 + g));
    };
    auto rdB = [&](int slot, int j, int mk) -> short8 {
        int brow = wc * 64 + j * 16 + qs;
        return *(const short8*)(lds + 98304 + slot * 16384 + swz(brow, mk * 4 + g));
    };

    float4v acc[4][4];
#pragma unroll
    for (int i = 0; i < 4; ++i)
#pragma unroll
        for (int j = 0; j < 4; ++j) acc[i][j] = (float4v){0.f, 0.f, 0.f, 0.f};

    short8 a[4][2], b[4][2];

    stage(0); stage(1);
    asm volatile("s_waitcnt vmcnt(6)" ::: "memory");
    __builtin_amdgcn_s_barrier();

    for (int t = 0; t < nt; ++t) {
        const int slot = t % 3;
#pragma unroll
        for (int i = 0; i < 4; ++i) {
            a[i][0] = rdA(slot, i, 0);
            a[i][1] = rdA(slot, i, 1);
        }
#pragma unroll
        for (int j = 0; j < 4; ++j) {
            b[j][0] = rdB(slot, j, 0);
            b[j][1] = rdB(slot, j, 1);
        }
        stage(t + 2);                      // 2-deep prefetch into slot (t+2)%3
        asm volatile("s_waitcnt lgkmcnt(0)" ::: "memory");
        __builtin_amdgcn_sched_barrier(0);
        __builtin_amdgcn_s_setprio(1);
#pragma unroll
        for (int i = 0; i < 4; ++i)
#pragma unroll
            for (int j = 0; j < 4; ++j) {
                acc[i][j] = __builtin_amdgcn_mfma_f32_16x16x32_bf16(
                    a[i][0], b[j][0], acc[i][j], 0, 0, 0);
                acc[i][j] = __builtin_amdgcn_mfma_f32_16x16x32_bf16(
                    a[i][1], b[j][1], acc[i][j], 0, 0, 0);
            }
        __builtin_amdgcn_s_setprio(0);
        asm volatile("s_waitcnt vmcnt(6)" ::: "memory");
        __builtin_amdgcn_s_barrier();
    }
    asm volatile("s_waitcnt vmcnt(0)" ::: "memory");

    // epilogue (wave tile 64x64)
#pragma unroll
    for (int mi = 0; mi < 4; ++mi) {
#pragma unroll
        for (int j = 0; j < 4; ++j) {
            int col = n0 + wc * 64 + j * 16 + qs;
            float bv = bias[col];
#pragma unroll
            for (int r = 0; r < 4; ++r) {
                int row = m0 + wr * 64 + mi * 16 + g * 4 + r;
                size_t idx = (size_t)row * N + col;
                float v = acc[mi][j][r] + bv;
                if (MODE == 0) {
                    if (col < EMB) v *= QSCALE;
                    outb[idx] = f2bf(v);
                } else if (MODE == 2) {
                    outb[idx] = f2bf(fmaxf(v, 0.f));
                } else if (MODE == 1) {
                    outf[idx] = v + res[idx];
                } else {
                    outf[idx] = v + bf2f(resb[idx]);
                }
            }
        }
    }
}

// ---------------------------------------------------------------- V transpose
__global__ __launch_bounds__(256) void vtrans(const unsigned short* __restrict__ qkv,
                                              unsigned short* __restrict__ vt) {
    const int bh = blockIdx.y, b = bh >> 4, h = bh & 15;
    const int t0 = blockIdx.x * 64;
    const int tid = threadIdx.x;
    __shared__ unsigned short lds[64][72];
#pragma unroll
    for (int rep = 0; rep < 2; ++rep) {
        int slot = rep * 256 + tid;
        int row = slot >> 3, cc = slot & 7;
        const unsigned short* g =
            qkv + ((size_t)(t0 + row) * BATCH + b) * 3072 + 2 * EMB + h * 64 + cc * 8;
        *(uint4v*)&lds[row][cc * 8] = *(const uint4v*)g;
    }
    __syncthreads();
#pragma unroll
    for (int rep = 0; rep < 2; ++rep) {
        int slot = rep * 256 + tid;
        int d = slot >> 3, tc = slot & 7;
        unsigned short tmp[8] __attribute__((aligned(16)));
#pragma unroll
        for (int j = 0; j < 8; ++j) tmp[j] = lds[tc * 8 + j][d];
        unsigned short* g = vt + ((size_t)bh * 64 + d) * S_LEN + t0 + tc * 8;
        *(uint4v*)g = *(const uint4v*)tmp;
    }
}

// ---------------------------------------------------------------- flash attention
// Swapped QK^T, exp2-unit softmax, defer-max THR=8, 24 KiB LDS -> 6 blocks/CU.
__global__ __launch_bounds__(256, 6) void attn(const unsigned short* __restrict__ qkv,
                                               const unsigned short* __restrict__ vt,
                                               unsigned short* __restrict__ ctx) {
    __shared__ char Ks[64 * 128];
    __shared__ char Vs[64 * 128];   // V^T tile: rows d, cols t
    __shared__ char QP[64 * 128];   // Q staging, then Ps[w] = QP + w*2048
    const int tid = threadIdx.x, lane = tid & 63, w = tid >> 6;
    const int bh = blockIdx.x & 127, b = bh >> 4, h = bh & 15;
    const int s0 = (blockIdx.x >> 7) * 64;
    const int g = lane >> 4, qs = lane & 15;

#pragma unroll
    for (int p = 0; p < 2; ++p) {   // Q stage (once)
        int ci = p * 256 + tid;
        int row = ci >> 3, c = (ci & 7) ^ (row & 7);
        gload_lds16(qkv + ((size_t)(s0 + row) * BATCH + b) * 3072 + h * 64 + c * 8,
                    QP + (p * 256 + w * 64) * 16);
    }
    __syncthreads();                // drains vmcnt: Q fully in LDS

    short8 qa0 = *(const short8*)(QP + swz(w * 16 + qs, 0 * 4 + g));
    short8 qa1 = *(const short8*)(QP + swz(w * 16 + qs, 1 * 4 + g));
    asm volatile("s_waitcnt lgkmcnt(0)" ::: "memory");
    __builtin_amdgcn_sched_barrier(0);          // reads complete before P overwrites
    char* Ps = QP + w * 2048;                   // alias: per-wave P scratch

    float4v O[4];
#pragma unroll
    for (int df = 0; df < 4; ++df) O[df] = (float4v){0.f, 0.f, 0.f, 0.f};
    float m_s = -1e30f;
    float l_s = 0.f;

    for (int t0 = 0; t0 < S_LEN; t0 += 64) {
        __syncthreads();
#pragma unroll
        for (int p = 0; p < 2; ++p) {
            int ci = p * 256 + tid;
            int row = ci >> 3, c = (ci & 7) ^ (row & 7);
            gload_lds16(qkv + ((size_t)(t0 + row) * BATCH + b) * 3072 + EMB + h * 64 + c * 8,
                        Ks + (p * 256 + w * 64) * 16);
            gload_lds16(vt + ((size_t)bh * 64 + row) * S_LEN + t0 + c * 8,
                        Vs + (p * 256 + w * 64) * 16);
        }
        __syncthreads();

        float4v Sf[4];
#pragma unroll
        for (int tf = 0; tf < 4; ++tf) Sf[tf] = (float4v){0.f, 0.f, 0.f, 0.f};
#pragma unroll
        for (int tf = 0; tf < 4; ++tf) {
            int kr = tf * 16 + qs;
            short8 kb0 = *(const short8*)(Ks + swz(kr, 0 * 4 + g));
            short8 kb1 = *(const short8*)(Ks + swz(kr, 1 * 4 + g));
            Sf[tf] = __builtin_amdgcn_mfma_f32_16x16x32_bf16(kb0, qa0, Sf[tf], 0, 0, 0);
            Sf[tf] = __builtin_amdgcn_mfma_f32_16x16x32_bf16(kb1, qa1, Sf[tf], 0, 0, 0);
        }

        float mx = fmaxf(fmaxf(Sf[0][0], Sf[0][1]), fmaxf(Sf[0][2], Sf[0][3]));
#pragma unroll
        for (int tf = 1; tf < 4; ++tf)
            mx = fmaxf(mx, fmaxf(fmaxf(Sf[tf][0], Sf[tf][1]),
                                 fmaxf(Sf[tf][2], Sf[tf][3])));
        mx = fmaxf(mx, __shfl_xor(mx, 16));
        mx = fmaxf(mx, __shfl_xor(mx, 32));

        if (!__all(mx - m_s <= 8.0f)) {
            float mnew = fmaxf(m_s, mx);
            float alpha = exp2v(m_s - mnew);
            m_s = mnew;
            l_s *= alpha;
#pragma unroll
            for (int r = 0; r < 4; ++r) {
                float ar = __shfl(alpha, 4 * g + r);
#pragma unroll
                for (int df = 0; df < 4; ++df) O[df][r] *= ar;
            }
        }

        float rs = 0.f;
#pragma unroll
        for (int tf = 0; tf < 4; ++tf) {
            float p0 = exp2v(Sf[tf][0] - m_s);
            float p1 = exp2v(Sf[tf][1] - m_s);
            float p2 = exp2v(Sf[tf][2] - m_s);
            float p3 = exp2v(Sf[tf][3] - m_s);
            rs += (p0 + p1) + (p2 + p3);
            uint2 pk = make_uint2(cvtpk_bf16(p0, p1), cvtpk_bf16(p2, p3));
            *(uint2*)(Ps + (qs << 7) +
                      (((2 * tf + (g >> 1)) ^ (qs & 7)) << 4) + ((g & 1) << 3)) = pk;
        }
        rs += __shfl_xor(rs, 16);
        rs += __shfl_xor(rs, 32);
        l_s += rs;

        asm volatile("s_waitcnt lgkmcnt(0)" ::: "memory");
        __builtin_amdgcn_sched_barrier(0);

#pragma unroll
        for (int mk = 0; mk < 2; ++mk) {
            short8 pa = *(const short8*)(Ps + swz(qs, mk * 4 + g));
#pragma unroll
            for (int df = 0; df < 4; ++df) {
                int vr = df * 16 + qs;
                short8 vb = *(const short8*)(Vs + swz(vr, mk * 4 + g));
                O[df] = __builtin_amdgcn_mfma_f32_16x16x32_bf16(pa, vb, O[df], 0, 0, 0);
            }
        }
    }

    float inv = __builtin_amdgcn_rcpf(l_s);
#pragma unroll
    for (int r = 0; r < 4; ++r) {
        float ir = __shfl(inv, 4 * g + r);
#pragma unroll
        for (int df = 0; df < 4; ++df) {
            int srow = s0 + w * 16 + g * 4 + r;
            int d    = df * 16 + qs;
            ctx[((size_t)srow * BATCH + b) * EMB + h * 64 + d] = f2bf(O[df][r] * ir);
        }
    }
}

// ---------------------------------------------------------------- LayerNorm (row=E)
__global__ __launch_bounds__(256) void ln_ker(const float* __restrict__ y,
                                              const float* __restrict__ g,
                                              const float* __restrict__ bta,
                                              float* __restrict__ xo,
                                              unsigned short* __restrict__ xb) {
    const int row = blockIdx.x, tid = threadIdx.x, lane = tid & 63, w = tid >> 6;
    float4 v = ((const float4*)(y + (size_t)row * EMB))[tid];
    float s = v.x + v.y + v.z + v.w;
    float q = v.x * v.x + v.y * v.y + v.z * v.z + v.w * v.w;
#pragma unroll
    for (int m = 1; m < 64; m <<= 1) {
        s += __shfl_xor(s, m);
        q += __shfl_xor(q, m);
    }
    __shared__ float ps[4], pq[4];
    if (lane == 0) { ps[w] = s; pq[w] = q; }
    __syncthreads();
    s = ps[0] + ps[1] + ps[2] + ps[3];
    q = pq[0] + pq[1] + pq[2] + pq[3];
    float mean = s * (1.f / EMB);
    float var  = q * (1.f / EMB) - mean * mean;
    float rstd = rsqrtf(var + 1e-5f);
    float4 gv = ((const float4*)g)[tid];
    float4 bv = ((const float4*)bta)[tid];
    float4 o;
    o.x = (v.x - mean) * rstd * gv.x + bv.x;
    o.y = (v.y - mean) * rstd * gv.y + bv.y;
    o.z = (v.z - mean) * rstd * gv.z + bv.z;
    o.w = (v.w - mean) * rstd * gv.w + bv.w;
    if (xo) ((float4*)(xo + (size_t)row * EMB))[tid] = o;
    if (xb) {
        us4 ob = { f2bf(o.x), f2bf(o.y), f2bf(o.z), f2bf(o.w) };
        ((us4*)(xb + (size_t)row * EMB))[tid] = ob;
    }
}

// ================================================================ host
// ws layout (MB): [0,24) weights | [24,72) qkvb | [72,88) srcbf/ctxb |
// [88,104) vtb | [24,40) xbf (reuse) | [40,104) hb (reuse). y in d_out.
extern "C" void kernel_launch(void* const* d_in, const int* in_sizes, int n_in,
                              void* d_out, int out_size, void* d_ws, size_t ws_size,
                              hipStream_t stream) {
    (void)in_sizes; (void)n_in; (void)out_size;
    const float* src       = (const float*)d_in[0];
    const float* in_proj_w = (const float*)d_in[1];
    const float* in_proj_b = (const float*)d_in[2];
    const float* out_w     = (const float*)d_in[3];
    const float* out_b     = (const float*)d_in[4];
    const float* ln1_g     = (const float*)d_in[5];
    const float* ln1_b     = (const float*)d_in[6];
    const float* ln2_g     = (const float*)d_in[7];
    const float* ln2_b     = (const float*)d_in[8];
    const float* w1        = (const float*)d_in[9];
    const float* b1        = (const float*)d_in[10];
    const float* w2        = (const float*)d_in[11];
    const float* b2        = (const float*)d_in[12];

    const size_t MB = 1u << 20;
    if (ws_size < 104 * MB) return;

    char* ws = (char*)d_ws;
    unsigned short* wqkvb = (unsigned short*)(ws);
    unsigned short* wob   = (unsigned short*)(ws + 6 * MB);
    unsigned short* w1b   = (unsigned short*)(ws + 8 * MB);
    unsigned short* w2b   = (unsigned short*)(ws + 16 * MB);
    unsigned short* qkvb  = (unsigned short*)(ws + 24 * MB);
    unsigned short* srcbf = (unsigned short*)(ws + 72 * MB);
    unsigned short* vtb   = (unsigned short*)(ws + 88 * MB);
    unsigned short* ctxb  = (unsigned short*)(ws + 72 * MB);
    unsigned short* xbf   = (unsigned short*)(ws + 24 * MB);
    unsigned short* hb    = (unsigned short*)(ws + 40 * MB);
    float*          yout  = (float*)d_out;

    auto castn = [&](const float* in, unsigned short* out, size_t n) {
        int n4 = (int)(n / 4);
        cast_bf<<<(n4 + 255) / 256, 256, 0, stream>>>(in, out, n4);
    };
    castn(src, srcbf, (size_t)ROWS * EMB);
    castn(in_proj_w, wqkvb, (size_t)3 * EMB * EMB);
    castn(out_w, wob, (size_t)EMB * EMB);
    castn(w1, w1b, (size_t)FFD * EMB);
    castn(w2, w2b, (size_t)EMB * FFD);

    // QKV projection (1-barrier 256x128, 768 blocks, q pre-scaled)
    gemm256n<0><<<(3 * EMB / 128) * 32, 512, 0, stream>>>(
        srcbf, wqkvb, in_proj_b, nullptr, nullptr,
        nullptr, qkvb, ROWS, 3 * EMB, EMB);

    vtrans<<<dim3(S_LEN / 64, BATCH * NH), 256, 0, stream>>>(qkvb, vtb);

    attn<<<(S_LEN / 64) * BATCH * NH, 256, 0, stream>>>(qkvb, vtb, ctxb);

    // out-projection + fp32 src residual -> y1 (in d_out)
    gemm256n<1><<<(EMB / 128) * 32, 512, 0, stream>>>(
        ctxb, wob, out_b, src, nullptr,
        yout, nullptr, ROWS, EMB, EMB);

    ln_ker<<<ROWS, 256, 0, stream>>>(yout, ln1_g, ln1_b, nullptr, xbf);

    // FF1 + ReLU (1-barrier 256x128, 1024 blocks)
    gemm256n<2><<<(FFD / 128) * 32, 512, 0, stream>>>(
        xbf, w1b, b1, nullptr, nullptr,
        nullptr, hb, ROWS, FFD, EMB);

    // FF2 + bf16 x residual -> y2 (in d_out)
    gemm256n<3><<<(EMB / 128) * 32, 512, 0, stream>>>(
        hb, w2b, b2, nullptr, xbf,
        yout, nullptr, ROWS, EMB, FFD);

    ln_ker<<<ROWS, 256, 0, stream>>>(yout, ln2_g, ln2_b, (float*)d_out, nullptr);
}

// Round 16
// 325.698 us; speedup vs baseline: 1.0686x; 1.0686x over previous
//
#include <hip/hip_runtime.h>

#define S_LEN 1024
#define BATCH 8
#define EMB   1024
#define NH    16
#define HD    64
#define FFD   4096
#define ROWS  (S_LEN*BATCH)   // 8192

typedef __attribute__((ext_vector_type(8))) short  short8;
typedef __attribute__((ext_vector_type(4))) float  float4v;
typedef __attribute__((ext_vector_type(4))) unsigned int uint4v;

struct alignas(8) us4 { unsigned short x, y, z, w; };

__device__ __forceinline__ unsigned short f2bf(float f) {
    unsigned int u = __float_as_uint(f);
    u += 0x7fffu + ((u >> 16) & 1u);       // round-to-nearest-even
    return (unsigned short)(u >> 16);
}
__device__ __forceinline__ float bf2f(unsigned short b) {
    return __uint_as_float((unsigned int)b << 16);
}
__device__ __forceinline__ unsigned int cvtpk_bf16(float lo, float hi) {
    unsigned int r;
    asm("v_cvt_pk_bf16_f32 %0, %1, %2" : "=v"(r) : "v"(lo), "v"(hi));
    return r;
}
__device__ __forceinline__ float exp2v(float x) {   // v_exp_f32 = 2^x
    float r;
    asm("v_exp_f32 %0, %1" : "=v"(r) : "v"(x));
    return r;
}

__device__ __forceinline__ void gload_lds16(const void* g, void* l) {
    __builtin_amdgcn_global_load_lds(
        (const __attribute__((address_space(1))) unsigned int*)g,
        (__attribute__((address_space(3))) unsigned int*)l, 16, 0, 0);
}

// LDS byte offset for element-row `row` (128B pitch = 64 bf16) and 16B chunk
// `chunk`, XOR-swizzled so ds_read_b128 phases are conflict-free.
__device__ __forceinline__ int swz(int row, int chunk) {
    return (row << 7) + ((chunk ^ (row & 7)) << 4);
}

// XCD-aware decode (T1): 1-D grid, gy must be 32 (ROWS/256). Blocks with the
// same m-panel (ly) share id%8 -> same XCD -> A-panel L2-filled once per XCD.
__device__ __forceinline__ void xcd_decode(int id, int& lx, int& ly) {
    int k = id & 7, j = id >> 3;
    ly = k * 4 + (j & 3);
    lx = j >> 2;
}

// ---------------------------------------------------------------- fused cast f32->bf16
// One launch for all five casts (5 independent contiguous segments).
__global__ __launch_bounds__(256) void cast_all(const float* __restrict__ s0, unsigned short* __restrict__ d0, int n0,
                                                const float* __restrict__ s1, unsigned short* __restrict__ d1, int n1,
                                                const float* __restrict__ s2, unsigned short* __restrict__ d2, int n2,
                                                const float* __restrict__ s3, unsigned short* __restrict__ d3, int n3,
                                                const float* __restrict__ s4, unsigned short* __restrict__ d4, int n4) {
    int i = blockIdx.x * 256 + threadIdx.x;   // index in float4 units
    const float* s; unsigned short* d;
    if (i < n0)                { s = s0; d = d0; }
    else if ((i -= n0) < n1)   { s = s1; d = d1; }
    else if ((i -= n1) < n2)   { s = s2; d = d2; }
    else if ((i -= n2) < n3)   { s = s3; d = d3; }
    else if ((i -= n3) < n4)   { s = s4; d = d4; }
    else return;
    float4 v = ((const float4*)s)[i];
    us4 o = { f2bf(v.x), f2bf(v.y), f2bf(v.z), f2bf(v.w) };
    ((us4*)d)[i] = o;
}

// ================================================================ 256x256 8-phase GEMM
// (r12-proven) C = A * B^T, bf16 out.
// MODE 0: (acc+bias)*(col<EMB?QSCALE:1)   MODE 2: relu(acc+bias)
// Counted vmcnt(2) once per K-tile at iteration END + s_barrier (race-safe).
#define QSCALE 0.18033688011112042f    // 0.125 * log2(e): softmax runs in exp2 units
template <int MODE>
__global__ __launch_bounds__(512, 2) void gemm256(const unsigned short* __restrict__ A,
                                                  const unsigned short* __restrict__ Bw,
                                                  const float* __restrict__ bias,
                                                  unsigned short* __restrict__ outb,
                                                  int M, int N, int K) {
    __shared__ char lds[131072];           // [0,64K) A slots, [64K,128K) B slots
    const int tid = threadIdx.x, lane = tid & 63, w = tid >> 6;
    const int wr = w >> 2, wc = w & 3;
    int lx, ly;
    xcd_decode(blockIdx.x, lx, ly);
    const int m0 = ly * 256, n0 = lx * 256;
    const int nt = K >> 6;

    size_t baseA[2], baseB[2];
    int ldsOff[2];
#pragma unroll
    for (int q = 0; q < 2; ++q) {
        int ci = q * 512 + tid;
        int row = ci >> 3;
        int c = (ci & 7) ^ (row & 7);
        baseA[q] = (size_t)(m0 + row) * K + c * 8;
        baseB[q] = (size_t)(n0 + row) * K + c * 8;
        ldsOff[q] = ci * 16;
    }

    auto stage = [&](int kt, int which) {
        int ktc = kt < nt ? kt : 0;        // clamp: garbage lands, never read
        int slot = kt & 1;
        if (which < 2) {
#pragma unroll
            for (int q = 0; q < 2; ++q)
                gload_lds16(A + baseA[q] + (size_t)which * 128 * K + (size_t)ktc * 64,
                            lds + slot * 32768 + which * 16384 + ldsOff[q]);
        } else {
            int h = which - 2;
#pragma unroll
            for (int q = 0; q < 2; ++q)
                gload_lds16(Bw + baseB[q] + (size_t)h * 128 * K + (size_t)ktc * 64,
                            lds + 65536 + slot * 32768 + h * 16384 + ldsOff[q]);
        }
    };

    auto rdA = [&](int slot, int mh, int i, int mk) -> short8 {
        int arow = wr * 128 + mh * 64 + i * 16 + (lane & 15);
        return *(const short8*)(lds + slot * 32768 + swz(arow, mk * 4 + (lane >> 4)));
    };
    auto rdB = [&](int slot, int nh, int j, int mk) -> short8 {
        int brow = wc * 64 + nh * 32 + j * 16 + (lane & 15);
        return *(const short8*)(lds + 65536 + slot * 32768 + swz(brow, mk * 4 + (lane >> 4)));
    };

    float4v acc[8][4];
#pragma unroll
    for (int i = 0; i < 8; ++i)
#pragma unroll
        for (int j = 0; j < 4; ++j) acc[i][j] = (float4v){0.f, 0.f, 0.f, 0.f};

    short8 a[4][2], b[2][2][2];

    stage(0, 0); stage(0, 1); stage(0, 2); stage(0, 3);
    stage(1, 0);
    asm volatile("s_waitcnt vmcnt(2)" ::: "memory");
    __builtin_amdgcn_s_barrier();

#define MFMA16(MH, NH)                                                          \
    __builtin_amdgcn_s_setprio(1);                                              \
    _Pragma("unroll")                                                           \
    for (int i = 0; i < 4; ++i)                                                 \
        _Pragma("unroll")                                                       \
        for (int j = 0; j < 2; ++j) {                                           \
            acc[(MH)*4+i][(NH)*2+j] = __builtin_amdgcn_mfma_f32_16x16x32_bf16(  \
                a[i][0], b[NH][j][0], acc[(MH)*4+i][(NH)*2+j], 0, 0, 0);        \
            acc[(MH)*4+i][(NH)*2+j] = __builtin_amdgcn_mfma_f32_16x16x32_bf16(  \
                a[i][1], b[NH][j][1], acc[(MH)*4+i][(NH)*2+j], 0, 0, 0);        \
        }                                                                       \
    __builtin_amdgcn_s_setprio(0);

    for (int t = 0; t < nt; ++t) {
        const int slot = t & 1;
#pragma unroll
        for (int i = 0; i < 4; ++i) {
            a[i][0] = rdA(slot, 0, i, 0);
            a[i][1] = rdA(slot, 0, i, 1);
        }
#pragma unroll
        for (int j = 0; j < 2; ++j) {
            b[0][j][0] = rdB(slot, 0, j, 0);
            b[0][j][1] = rdB(slot, 0, j, 1);
        }
        stage(t + 1, 1);
        __builtin_amdgcn_s_barrier();
        asm volatile("s_waitcnt lgkmcnt(0)" ::: "memory");
        __builtin_amdgcn_sched_barrier(0);
        MFMA16(0, 0)
        __builtin_amdgcn_s_barrier();
#pragma unroll
        for (int j = 0; j < 2; ++j) {
            b[1][j][0] = rdB(slot, 1, j, 0);
            b[1][j][1] = rdB(slot, 1, j, 1);
        }
        stage(t + 1, 2);
        __builtin_amdgcn_s_barrier();
        asm volatile("s_waitcnt lgkmcnt(0)" ::: "memory");
        __builtin_amdgcn_sched_barrier(0);
        MFMA16(0, 1)
        __builtin_amdgcn_s_barrier();
#pragma unroll
        for (int i = 0; i < 4; ++i) {
            a[i][0] = rdA(slot, 1, i, 0);
            a[i][1] = rdA(slot, 1, i, 1);
        }
        stage(t + 1, 3);
        __builtin_amdgcn_s_barrier();
        asm volatile("s_waitcnt lgkmcnt(0)" ::: "memory");
        __builtin_amdgcn_sched_barrier(0);
        MFMA16(1, 1)
        __builtin_amdgcn_s_barrier();
        stage(t + 2, 0);
        MFMA16(1, 0)
        asm volatile("s_waitcnt vmcnt(2)" ::: "memory");
        __builtin_amdgcn_s_barrier();
    }
#undef MFMA16
    asm volatile("s_waitcnt vmcnt(0)" ::: "memory");

#pragma unroll
    for (int mi = 0; mi < 8; ++mi) {
#pragma unroll
        for (int nj = 0; nj < 4; ++nj) {
            int col = n0 + wc * 64 + nj * 16 + (lane & 15);
            float bv = bias[col];
#pragma unroll
            for (int r = 0; r < 4; ++r) {
                int row = m0 + wr * 128 + mi * 16 + (lane >> 4) * 4 + r;
                size_t idx = (size_t)row * N + col;
                float v = acc[mi][nj][r] + bv;
                if (MODE == 0) {
                    if (col < EMB) v *= QSCALE;
                    outb[idx] = f2bf(v);
                } else {
                    outb[idx] = f2bf(fmaxf(v, 0.f));
                }
            }
        }
    }
}

// ================================================================ 256x128 1-barrier GEMM
// (r12 winner) Triple-buffered LDS, 2-deep prefetch, one barrier + one
// lgkmcnt(0) + one counted vmcnt(6) per K-tile. 4M x 2N, wave owns 64x64.
// MODE 1: res fp32 (out-proj + src)   MODE 3: res bf16 (FF2 + x)
template <int MODE>
__global__ __launch_bounds__(512, 2) void gemm256n(const unsigned short* __restrict__ A,
                                                   const unsigned short* __restrict__ Bw,
                                                   const float* __restrict__ bias,
                                                   const float* __restrict__ res,
                                                   const unsigned short* __restrict__ resb,
                                                   float* __restrict__ outf,
                                                   int M, int N, int K) {
    __shared__ char lds[147456];   // A: [0,96K) 3x32K slots; B: [96K,144K) 3x16K
    const int tid = threadIdx.x, lane = tid & 63, w = tid >> 6;
    const int wr = w >> 1, wc = w & 1;     // 4M x 2N
    int lx, ly;
    xcd_decode(blockIdx.x, lx, ly);
    const int m0 = ly * 256, n0 = lx * 128;
    const int nt = K >> 6;
    const int g = lane >> 4, qs = lane & 15;

    size_t baseA[4], baseB[2];
    int ldsOffA[4], ldsOffB[2];
#pragma unroll
    for (int q = 0; q < 4; ++q) {
        int ci = q * 512 + tid;
        int row = ci >> 3;                 // 0..255
        int c = (ci & 7) ^ (row & 7);
        baseA[q] = (size_t)(m0 + row) * K + c * 8;
        ldsOffA[q] = ci * 16;
    }
#pragma unroll
    for (int q = 0; q < 2; ++q) {
        int ci = q * 512 + tid;
        int row = ci >> 3;                 // 0..127
        int c = (ci & 7) ^ (row & 7);
        baseB[q] = (size_t)(n0 + row) * K + c * 8;
        ldsOffB[q] = ci * 16;
    }

    auto stage = [&](int kt) {
        int ktc = kt < nt ? kt : 0;        // clamp: garbage lands, never read
        int slot = kt % 3;
#pragma unroll
        for (int q = 0; q < 4; ++q)
            gload_lds16(A + baseA[q] + (size_t)ktc * 64,
                        lds + slot * 32768 + ldsOffA[q]);
#pragma unroll
        for (int q = 0; q < 2; ++q)
            gload_lds16(Bw + baseB[q] + (size_t)ktc * 64,
                        lds + 98304 + slot * 16384 + ldsOffB[q]);
    };

    auto rdA = [&](int slot, int i, int mk) -> short8 {
        int arow = wr * 64 + i * 16 + qs;
        return *(const short8*)(lds + slot * 32768 + swz(arow, mk * 4 + g));
    };
    auto rdB = [&](int slot, int j, int mk) -> short8 {
        int brow = wc * 64 + j * 16 + qs;
        return *(const short8*)(lds + 98304 + slot * 16384 + swz(brow, mk * 4 + g));
    };

    float4v acc[4][4];
#pragma unroll
    for (int i = 0; i < 4; ++i)
#pragma unroll
        for (int j = 0; j < 4; ++j) acc[i][j] = (float4v){0.f, 0.f, 0.f, 0.f};

    short8 a[4][2], b[4][2];

    stage(0); stage(1);
    asm volatile("s_waitcnt vmcnt(6)" ::: "memory");
    __builtin_amdgcn_s_barrier();

    for (int t = 0; t < nt; ++t) {
        const int slot = t % 3;
#pragma unroll
        for (int i = 0; i < 4; ++i) {
            a[i][0] = rdA(slot, i, 0);
            a[i][1] = rdA(slot, i, 1);
        }
#pragma unroll
        for (int j = 0; j < 4; ++j) {
            b[j][0] = rdB(slot, j, 0);
            b[j][1] = rdB(slot, j, 1);
        }
        stage(t + 2);                      // 2-deep prefetch into slot (t+2)%3
        asm volatile("s_waitcnt lgkmcnt(0)" ::: "memory");
        __builtin_amdgcn_sched_barrier(0);
        __builtin_amdgcn_s_setprio(1);
#pragma unroll
        for (int i = 0; i < 4; ++i)
#pragma unroll
            for (int j = 0; j < 4; ++j) {
                acc[i][j] = __builtin_amdgcn_mfma_f32_16x16x32_bf16(
                    a[i][0], b[j][0], acc[i][j], 0, 0, 0);
                acc[i][j] = __builtin_amdgcn_mfma_f32_16x16x32_bf16(
                    a[i][1], b[j][1], acc[i][j], 0, 0, 0);
            }
        __builtin_amdgcn_s_setprio(0);
        asm volatile("s_waitcnt vmcnt(6)" ::: "memory");
        __builtin_amdgcn_s_barrier();
    }
    asm volatile("s_waitcnt vmcnt(0)" ::: "memory");

#pragma unroll
    for (int mi = 0; mi < 4; ++mi) {
#pragma unroll
        for (int j = 0; j < 4; ++j) {
            int col = n0 + wc * 64 + j * 16 + qs;
            float bv = bias[col];
#pragma unroll
            for (int r = 0; r < 4; ++r) {
                int row = m0 + wr * 64 + mi * 16 + g * 4 + r;
                size_t idx = (size_t)row * N + col;
                float v = acc[mi][j][r] + bv;
                if (MODE == 1) outf[idx] = v + res[idx];
                else           outf[idx] = v + bf2f(resb[idx]);
            }
        }
    }
}

// ---------------------------------------------------------------- V transpose
__global__ __launch_bounds__(256) void vtrans(const unsigned short* __restrict__ qkv,
                                              unsigned short* __restrict__ vt) {
    const int bh = blockIdx.y, b = bh >> 4, h = bh & 15;
    const int t0 = blockIdx.x * 64;
    const int tid = threadIdx.x;
    __shared__ unsigned short lds[64][72];
#pragma unroll
    for (int rep = 0; rep < 2; ++rep) {
        int slot = rep * 256 + tid;
        int row = slot >> 3, cc = slot & 7;
        const unsigned short* g =
            qkv + ((size_t)(t0 + row) * BATCH + b) * 3072 + 2 * EMB + h * 64 + cc * 8;
        *(uint4v*)&lds[row][cc * 8] = *(const uint4v*)g;
    }
    __syncthreads();
#pragma unroll
    for (int rep = 0; rep < 2; ++rep) {
        int slot = rep * 256 + tid;
        int d = slot >> 3, tc = slot & 7;
        unsigned short tmp[8] __attribute__((aligned(16)));
#pragma unroll
        for (int j = 0; j < 8; ++j) tmp[j] = lds[tc * 8 + j][d];
        unsigned short* g = vt + ((size_t)bh * 64 + d) * S_LEN + t0 + tc * 8;
        *(uint4v*)g = *(const uint4v*)tmp;
    }
}

// ---------------------------------------------------------------- flash attention
// Swapped QK^T, exp2-unit softmax, defer-max THR=8, 24 KiB LDS -> 6 blocks/CU.
__global__ __launch_bounds__(256, 6) void attn(const unsigned short* __restrict__ qkv,
                                               const unsigned short* __restrict__ vt,
                                               unsigned short* __restrict__ ctx) {
    __shared__ char Ks[64 * 128];
    __shared__ char Vs[64 * 128];   // V^T tile: rows d, cols t
    __shared__ char QP[64 * 128];   // Q staging, then Ps[w] = QP + w*2048
    const int tid = threadIdx.x, lane = tid & 63, w = tid >> 6;
    const int bh = blockIdx.x & 127, b = bh >> 4, h = bh & 15;
    const int s0 = (blockIdx.x >> 7) * 64;
    const int g = lane >> 4, qs = lane & 15;

#pragma unroll
    for (int p = 0; p < 2; ++p) {   // Q stage (once)
        int ci = p * 256 + tid;
        int row = ci >> 3, c = (ci & 7) ^ (row & 7);
        gload_lds16(qkv + ((size_t)(s0 + row) * BATCH + b) * 3072 + h * 64 + c * 8,
                    QP + (p * 256 + w * 64) * 16);
    }
    __syncthreads();                // drains vmcnt: Q fully in LDS

    short8 qa0 = *(const short8*)(QP + swz(w * 16 + qs, 0 * 4 + g));
    short8 qa1 = *(const short8*)(QP + swz(w * 16 + qs, 1 * 4 + g));
    asm volatile("s_waitcnt lgkmcnt(0)" ::: "memory");
    __builtin_amdgcn_sched_barrier(0);          // reads complete before P overwrites
    char* Ps = QP + w * 2048;                   // alias: per-wave P scratch

    float4v O[4];
#pragma unroll
    for (int df = 0; df < 4; ++df) O[df] = (float4v){0.f, 0.f, 0.f, 0.f};
    float m_s = -1e30f;
    float l_s = 0.f;

    for (int t0 = 0; t0 < S_LEN; t0 += 64) {
        __syncthreads();
#pragma unroll
        for (int p = 0; p < 2; ++p) {
            int ci = p * 256 + tid;
            int row = ci >> 3, c = (ci & 7) ^ (row & 7);
            gload_lds16(qkv + ((size_t)(t0 + row) * BATCH + b) * 3072 + EMB + h * 64 + c * 8,
                        Ks + (p * 256 + w * 64) * 16);
            gload_lds16(vt + ((size_t)bh * 64 + row) * S_LEN + t0 + c * 8,
                        Vs + (p * 256 + w * 64) * 16);
        }
        __syncthreads();

        float4v Sf[4];
#pragma unroll
        for (int tf = 0; tf < 4; ++tf) Sf[tf] = (float4v){0.f, 0.f, 0.f, 0.f};
#pragma unroll
        for (int tf = 0; tf < 4; ++tf) {
            int kr = tf * 16 + qs;
            short8 kb0 = *(const short8*)(Ks + swz(kr, 0 * 4 + g));
            short8 kb1 = *(const short8*)(Ks + swz(kr, 1 * 4 + g));
            Sf[tf] = __builtin_amdgcn_mfma_f32_16x16x32_bf16(kb0, qa0, Sf[tf], 0, 0, 0);
            Sf[tf] = __builtin_amdgcn_mfma_f32_16x16x32_bf16(kb1, qa1, Sf[tf], 0, 0, 0);
        }

        float mx = fmaxf(fmaxf(Sf[0][0], Sf[0][1]), fmaxf(Sf[0][2], Sf[0][3]));
#pragma unroll
        for (int tf = 1; tf < 4; ++tf)
            mx = fmaxf(mx, fmaxf(fmaxf(Sf[tf][0], Sf[tf][1]),
                                 fmaxf(Sf[tf][2], Sf[tf][3])));
        mx = fmaxf(mx, __shfl_xor(mx, 16));
        mx = fmaxf(mx, __shfl_xor(mx, 32));

        if (!__all(mx - m_s <= 8.0f)) {
            float mnew = fmaxf(m_s, mx);
            float alpha = exp2v(m_s - mnew);
            m_s = mnew;
            l_s *= alpha;
#pragma unroll
            for (int r = 0; r < 4; ++r) {
                float ar = __shfl(alpha, 4 * g + r);
#pragma unroll
                for (int df = 0; df < 4; ++df) O[df][r] *= ar;
            }
        }

        float rs = 0.f;
#pragma unroll
        for (int tf = 0; tf < 4; ++tf) {
            float p0 = exp2v(Sf[tf][0] - m_s);
            float p1 = exp2v(Sf[tf][1] - m_s);
            float p2 = exp2v(Sf[tf][2] - m_s);
            float p3 = exp2v(Sf[tf][3] - m_s);
            rs += (p0 + p1) + (p2 + p3);
            uint2 pk = make_uint2(cvtpk_bf16(p0, p1), cvtpk_bf16(p2, p3));
            *(uint2*)(Ps + (qs << 7) +
                      (((2 * tf + (g >> 1)) ^ (qs & 7)) << 4) + ((g & 1) << 3)) = pk;
        }
        rs += __shfl_xor(rs, 16);
        rs += __shfl_xor(rs, 32);
        l_s += rs;

        asm volatile("s_waitcnt lgkmcnt(0)" ::: "memory");
        __builtin_amdgcn_sched_barrier(0);

#pragma unroll
        for (int mk = 0; mk < 2; ++mk) {
            short8 pa = *(const short8*)(Ps + swz(qs, mk * 4 + g));
#pragma unroll
            for (int df = 0; df < 4; ++df) {
                int vr = df * 16 + qs;
                short8 vb = *(const short8*)(Vs + swz(vr, mk * 4 + g));
                O[df] = __builtin_amdgcn_mfma_f32_16x16x32_bf16(pa, vb, O[df], 0, 0, 0);
            }
        }
    }

    float inv = __builtin_amdgcn_rcpf(l_s);
#pragma unroll
    for (int r = 0; r < 4; ++r) {
        float ir = __shfl(inv, 4 * g + r);
#pragma unroll
        for (int df = 0; df < 4; ++df) {
            int srow = s0 + w * 16 + g * 4 + r;
            int d    = df * 16 + qs;
            ctx[((size_t)srow * BATCH + b) * EMB + h * 64 + d] = f2bf(O[df][r] * ir);
        }
    }
}

// ---------------------------------------------------------------- LayerNorm (row=E)
__global__ __launch_bounds__(256) void ln_ker(const float* __restrict__ y,
                                              const float* __restrict__ g,
                                              const float* __restrict__ bta,
                                              float* __restrict__ xo,
                                              unsigned short* __restrict__ xb) {
    const int row = blockIdx.x, tid = threadIdx.x, lane = tid & 63, w = tid >> 6;
    float4 v = ((const float4*)(y + (size_t)row * EMB))[tid];
    float s = v.x + v.y + v.z + v.w;
    float q = v.x * v.x + v.y * v.y + v.z * v.z + v.w * v.w;
#pragma unroll
    for (int m = 1; m < 64; m <<= 1) {
        s += __shfl_xor(s, m);
        q += __shfl_xor(q, m);
    }
    __shared__ float ps[4], pq[4];
    if (lane == 0) { ps[w] = s; pq[w] = q; }
    __syncthreads();
    s = ps[0] + ps[1] + ps[2] + ps[3];
    q = pq[0] + pq[1] + pq[2] + pq[3];
    float mean = s * (1.f / EMB);
    float var  = q * (1.f / EMB) - mean * mean;
    float rstd = rsqrtf(var + 1e-5f);
    float4 gv = ((const float4*)g)[tid];
    float4 bv = ((const float4*)bta)[tid];
    float4 o;
    o.x = (v.x - mean) * rstd * gv.x + bv.x;
    o.y = (v.y - mean) * rstd * gv.y + bv.y;
    o.z = (v.z - mean) * rstd * gv.z + bv.z;
    o.w = (v.w - mean) * rstd * gv.w + bv.w;
    if (xo) ((float4*)(xo + (size_t)row * EMB))[tid] = o;
    if (xb) {
        us4 ob = { f2bf(o.x), f2bf(o.y), f2bf(o.z), f2bf(o.w) };
        ((us4*)(xb + (size_t)row * EMB))[tid] = ob;
    }
}

// ================================================================ host
// ws layout (MB): [0,24) weights | [24,72) qkvb | [72,88) srcbf/ctxb |
// [88,104) vtb | [24,40) xbf (reuse) | [40,104) hb (reuse). y in d_out.
extern "C" void kernel_launch(void* const* d_in, const int* in_sizes, int n_in,
                              void* d_out, int out_size, void* d_ws, size_t ws_size,
                              hipStream_t stream) {
    (void)in_sizes; (void)n_in; (void)out_size;
    const float* src       = (const float*)d_in[0];
    const float* in_proj_w = (const float*)d_in[1];
    const float* in_proj_b = (const float*)d_in[2];
    const float* out_w     = (const float*)d_in[3];
    const float* out_b     = (const float*)d_in[4];
    const float* ln1_g     = (const float*)d_in[5];
    const float* ln1_b     = (const float*)d_in[6];
    const float* ln2_g     = (const float*)d_in[7];
    const float* ln2_b     = (const float*)d_in[8];
    const float* w1        = (const float*)d_in[9];
    const float* b1        = (const float*)d_in[10];
    const float* w2        = (const float*)d_in[11];
    const float* b2        = (const float*)d_in[12];

    const size_t MB = 1u << 20;
    if (ws_size < 104 * MB) return;

    char* ws = (char*)d_ws;
    unsigned short* wqkvb = (unsigned short*)(ws);
    unsigned short* wob   = (unsigned short*)(ws + 6 * MB);
    unsigned short* w1b   = (unsigned short*)(ws + 8 * MB);
    unsigned short* w2b   = (unsigned short*)(ws + 16 * MB);
    unsigned short* qkvb  = (unsigned short*)(ws + 24 * MB);
    unsigned short* srcbf = (unsigned short*)(ws + 72 * MB);
    unsigned short* vtb   = (unsigned short*)(ws + 88 * MB);
    unsigned short* ctxb  = (unsigned short*)(ws + 72 * MB);
    unsigned short* xbf   = (unsigned short*)(ws + 24 * MB);
    unsigned short* hb    = (unsigned short*)(ws + 40 * MB);
    float*          yout  = (float*)d_out;

    // fused cast: src, in_proj_w, out_w, w1, w2 (counts in float4 units)
    const int c0 = ROWS * EMB / 4;           // 2097152
    const int c1 = 3 * EMB * EMB / 4;        // 786432
    const int c2 = EMB * EMB / 4;            // 262144
    const int c3 = FFD * EMB / 4;            // 1048576
    const int c4 = EMB * FFD / 4;            // 1048576
    const int ctot = c0 + c1 + c2 + c3 + c4; // 5242880 -> 20480 blocks
    cast_all<<<ctot / 256, 256, 0, stream>>>(
        src, srcbf, c0, in_proj_w, wqkvb, c1, out_w, wob, c2,
        w1, w1b, c3, w2, w2b, c4);

    // QKV projection (8-phase 256², XCD-swizzled, q pre-scaled by 0.125*log2e)
    gemm256<0><<<(3 * EMB / 256) * 32, 512, 0, stream>>>(
        srcbf, wqkvb, in_proj_b, qkvb, ROWS, 3 * EMB, EMB);

    vtrans<<<dim3(S_LEN / 64, BATCH * NH), 256, 0, stream>>>(qkvb, vtb);

    attn<<<(S_LEN / 64) * BATCH * NH, 256, 0, stream>>>(qkvb, vtb, ctxb);

    // out-projection + fp32 src residual -> y1 (in d_out), 256x128 1-barrier
    gemm256n<1><<<(EMB / 128) * 32, 512, 0, stream>>>(
        ctxb, wob, out_b, src, nullptr, yout, ROWS, EMB, EMB);

    ln_ker<<<ROWS, 256, 0, stream>>>(yout, ln1_g, ln1_b, nullptr, xbf);

    // FF1 + ReLU (8-phase 256², XCD-swizzled)
    gemm256<2><<<(FFD / 256) * 32, 512, 0, stream>>>(
        xbf, w1b, b1, hb, ROWS, FFD, EMB);

    // FF2 + bf16 x residual -> y2 (in d_out), 256x128 1-barrier, XCD-swizzled
    gemm256n<3><<<(EMB / 128) * 32, 512, 0, stream>>>(
        hb, w2b, b2, nullptr, xbf, yout, ROWS, EMB, FFD);

    ln_ker<<<ROWS, 256, 0, stream>>>(yout, ln2_g, ln2_b, (float*)d_out, nullptr);
}